// Round 20
// baseline (40.655 us; speedup 1.0000x reference)
//
#include <hip/hip_runtime.h>
#include <math.h>

#define IMG_H 512
#define IMG_W 512
#define TH 8                 // output rows per band
#define KR 5                 // radius
#define KS 11                // taps
#define NR (TH + 2 * KR)     // 18 input rows per band
#define LWE 524              // f32x4 elems per row: cols -6..517 at e=col+6
#define NTHREADS 512
#define NBANDS (IMG_H / TH)  // 64
#define NPLANES 48
#define NBLK (NBANDS * NPLANES)   // 3072, divisible by 8

typedef float f32x4 __attribute__((ext_vector_type(4)));

struct W11 { float w[KS]; };   // gaussian taps

// 16B-elem XOR swizzle (elem = one f32x4). Phase-B reads have lane stride 8
// elems -> XOR spreads 8-elem blocks across bank quads (dense); phase-A
// stride-1 writes stay dense. Never escapes an aligned 8-elem block.
__device__ __forceinline__ int swz(int e) { return e ^ ((e >> 3) & 7); }

// Fused SSIM band kernel: one 512x8 full-width band per block, 512 threads.
// == R14/R19 (measured best, 40.5us) with ONE change: a single multi-operand
// asm pin after the load loop forces all 36 row values CO-LIVE -> the 36
// global loads must issue back-to-back with one vmcnt wait, instead of being
// sunk one-by-one into the vconv (the latency serialization the R17 ablation
// measured at ~12us). VGPR rises to ~80-100: free, since occupancy is
// LDS-bound (67KB -> 2 blocks/CU) and the (512,4) cap is 128.
__global__ __launch_bounds__(NTHREADS, 4)
void ssim_tile_kernel(const float* __restrict__ img1, const float* __restrict__ img2,
                      float* __restrict__ bsums, W11 wt) {
    __shared__ f32x4 sE[TH][LWE];   // 67,072 B
    __shared__ float redw[NTHREADS / 64];

    // XCD-aware bijective remap (NBLK % 8 == 0): each XCD sweeps 6 whole
    // planes in ascending band order -> band halos hit its own L2.
    const int bid   = blockIdx.x;
    const int sbid  = (bid & 7) * (NBLK / 8) + (bid >> 3);
    const int plane = sbid >> 6;              // sbid / NBANDS
    const int band  = sbid & (NBANDS - 1);

    const int r0 = band * TH - KR;
    const float* __restrict__ p1 = img1 + (size_t)plane * (IMG_H * IMG_W);
    const float* __restrict__ p2 = img2 + (size_t)plane * (IMG_H * IMG_W);
    const int tid = threadIdx.x;

    // Zero-fill the 12 alignment-halo elems (cols -6..-1, 512..517) x 8 rows.
    if (tid < 128) {
        const int h = tid & 15;
        if (h < 12) {
            const int r = tid >> 4;                    // 0..7
            const int e = (h < 6) ? h : (512 + h);
            sE[r][swz(e)] = (f32x4){0.f, 0.f, 0.f, 0.f};
        }
    }

    // ---- Phase A: vertical 11-tap conv, one column per thread ----
    float av[NR], bv[NR];
    {
        const float* __restrict__ g1 = p1 + tid;
        const float* __restrict__ g2 = p2 + tid;
        if (r0 >= 0 && r0 + NR <= IMG_H) {
            #pragma unroll
            for (int j = 0; j < NR; ++j) {
                av[j] = g1[(r0 + j) * IMG_W];
                bv[j] = g2[(r0 + j) * IMG_W];
            }
        } else {
            #pragma unroll
            for (int j = 0; j < NR; ++j) {
                const int  rr  = r0 + j;
                const bool ok  = (rr >= 0) && (rr < IMG_H);   // block-uniform
                const int  rrc = min(max(rr, 0), IMG_H - 1);
                const float a = g1[rrc * IMG_W];
                const float b = g2[rrc * IMG_W];
                av[j] = ok ? a : 0.f;
                bv[j] = ok ? b : 0.f;
            }
        }
    }
    // Force ALL 36 loads in flight simultaneously: one statement, 36 operands
    // -> no load may sink past it; one vmcnt wait instead of 36 chains.
    asm volatile("" ::
        "v"(av[0]), "v"(av[1]), "v"(av[2]), "v"(av[3]), "v"(av[4]), "v"(av[5]),
        "v"(av[6]), "v"(av[7]), "v"(av[8]), "v"(av[9]), "v"(av[10]), "v"(av[11]),
        "v"(av[12]), "v"(av[13]), "v"(av[14]), "v"(av[15]), "v"(av[16]), "v"(av[17]),
        "v"(bv[0]), "v"(bv[1]), "v"(bv[2]), "v"(bv[3]), "v"(bv[4]), "v"(bv[5]),
        "v"(bv[6]), "v"(bv[7]), "v"(bv[8]), "v"(bv[9]), "v"(bv[10]), "v"(bv[11]),
        "v"(bv[12]), "v"(bv[13]), "v"(bv[14]), "v"(bv[15]), "v"(bv[16]), "v"(bv[17]));

    f32x4 acc[TH];
    #pragma unroll
    for (int r = 0; r < TH; ++r) acc[r] = (f32x4){0.f, 0.f, 0.f, 0.f};

    #pragma unroll
    for (int j = 0; j < NR; ++j) {
        const float a = av[j], b = bv[j];
        f32x4 pv; pv.x = a; pv.y = b;
        pv.z = fmaf(a, a, b * b); pv.w = a * b;
        #pragma unroll
        for (int r = 0; r < TH; ++r) {
            const int k = j - r;                      // compile-time
            if (k >= 0 && k < KS) {
                f32x4 wv; wv.x = wt.w[k]; wv.y = wt.w[k];
                wv.z = wt.w[k]; wv.w = wt.w[k];
                acc[r] = __builtin_elementwise_fma(wv, pv, acc[r]);
            }
        }
    }
    {
        const int slot = swz(tid + 6);
        #pragma unroll
        for (int r = 0; r < TH; ++r) sE[r][slot] = acc[r];
    }
    __syncthreads();

    // ---- Phase B: horizontal conv + SSIM map; 1 row x 8 consecutive cols ----
    const float C1f = 0.0001f;   // 0.01^2
    const float C2f = 0.0009f;   // 0.03^2
    const int g  = tid >> 6;             // 8 rows x 64 lanes
    const int L  = tid & 63;
    const int eb = (L << 3) + 1;         // cols 8L..8L+7 need elems eb..eb+17

    f32x4 x[18];
    #pragma unroll
    for (int i = 0; i < 18; ++i) x[i] = sE[g][swz(eb + i)];

    float lsum = 0.f;
    #pragma unroll
    for (int jj = 0; jj < 8; ++jj) {
        f32x4 c;
        {
            f32x4 wv; wv.x = wt.w[0]; wv.y = wt.w[0];
            wv.z = wt.w[0]; wv.w = wt.w[0];
            c = wv * x[jj];
        }
        #pragma unroll
        for (int k = 1; k < KS; ++k) {
            f32x4 wv; wv.x = wt.w[k]; wv.y = wt.w[k];
            wv.z = wt.w[k]; wv.w = wt.w[k];
            c = __builtin_elementwise_fma(wv, x[jj + k], c);
        }
        const float m1 = c.x, m2 = c.y;
        const float pp = c.z, ab = c.w;
        const float mu11 = m1 * m1;
        const float mu22 = m2 * m2;
        const float mu12 = m1 * m2;
        const float t     = mu11 + mu22;
        const float sigpp = pp - t;              // sigma1_sq + sigma2_sq
        const float sig12 = ab - mu12;
        const float num = fmaf(2.f, mu12, C1f) * fmaf(2.f, sig12, C2f);
        const float den = (t + C1f) * (sigpp + C2f);
        lsum = fmaf(num, __builtin_amdgcn_rcpf(den), lsum);
    }

    // ---- reduce: wave shuffle, then per-wave partials ----
    #pragma unroll
    for (int off = 32; off > 0; off >>= 1) lsum += __shfl_down(lsum, off);
    if ((tid & 63) == 0) redw[tid >> 6] = lsum;
    __syncthreads();
    if (tid == 0) {
        float t = 0.f;
        #pragma unroll
        for (int w = 0; w < NTHREADS / 64; ++w) t += redw[w];
        bsums[sbid] = t;
    }
}

// Final reduce in double (fp32 sequential sum of the 1.26e7-magnitude total
// would exceed the 2.6e-4 threshold).
__global__ __launch_bounds__(256)
void ssim_reduce_kernel(const float4* __restrict__ bsums, int n4,
                        float* __restrict__ out, double inv_count) {
    __shared__ double red[256];
    double acc = 0.0;
    for (int i = threadIdx.x; i < n4; i += 256) {
        const float4 v = bsums[i];
        acc += (double)v.x + (double)v.y + (double)v.z + (double)v.w;
    }
    red[threadIdx.x] = acc;
    __syncthreads();
    #pragma unroll
    for (int off = 128; off > 0; off >>= 1) {
        if (threadIdx.x < off) red[threadIdx.x] += red[threadIdx.x + off];
        __syncthreads();
    }
    if (threadIdx.x == 0) out[0] = (float)(red[0] * inv_count);
}

extern "C" void kernel_launch(void* const* d_in, const int* in_sizes, int n_in,
                              void* d_out, int out_size, void* d_ws, size_t ws_size,
                              hipStream_t stream) {
    const float* img1 = (const float*)d_in[0];
    const float* img2 = (const float*)d_in[1];
    float* out = (float*)d_out;
    float* bsums = (float*)d_ws;

    // Gaussian weights, computed in double like the numpy reference.
    W11 wt;
    {
        double g[KS], sum = 0.0;
        for (int i = 0; i < KS; ++i) {
            const double x = (double)(i - KR);
            g[i] = exp(-(x * x) / (2.0 * 1.5 * 1.5));
            sum += g[i];
        }
        for (int i = 0; i < KS; ++i) wt.w[i] = (float)(g[i] / sum);
    }

    ssim_tile_kernel<<<dim3(NBLK), NTHREADS, 0, stream>>>(img1, img2, bsums, wt);

    const double inv_count = 1.0 / ((double)NPLANES * IMG_H * IMG_W);
    ssim_reduce_kernel<<<1, 256, 0, stream>>>((const float4*)bsums, NBLK / 4,
                                              out, inv_count);
}

// Round 21
// 40.571 us; speedup vs baseline: 1.0021x; 1.0021x over previous
//
#include <hip/hip_runtime.h>
#include <math.h>

#define IMG_H 512
#define IMG_W 512
#define TH 8                 // output rows per band
#define KR 5                 // radius
#define KS 11                // taps
#define NR (TH + 2 * KR)     // 18 input rows per band
#define LWE 524              // f32x4 elems per row: cols -6..517 at e=col+6
#define NTHREADS 512
#define NBANDS (IMG_H / TH)  // 64
#define NPLANES 48
#define NBLK (NBANDS * NPLANES)   // 3072, divisible by 8

typedef float f32x4 __attribute__((ext_vector_type(4)));

struct W11 { float w[KS]; };   // gaussian taps

// 16B-elem XOR swizzle (elem = one f32x4). Phase-B reads have lane stride 8
// elems -> XOR spreads 8-elem blocks across bank quads (dense); phase-A
// stride-1 writes stay dense. Never escapes an aligned 8-elem block.
__device__ __forceinline__ int swz(int e) { return e ^ ((e >> 3) & 7); }

// Fused SSIM band kernel: one 512x8 full-width band per block, 512 threads.
// == R19 (measured best, 40.5us) with ONE change: the 18-element hconv
// window is PINNED co-live after the LDS read loop. Evidence: x[18] needs 72
// VGPRs but the kernel used only 52 -> the compiler was re-reading LDS
// just-in-time inside the output loop, chaining ds_read latency (~120cy)
// per step with only 4 waves/SIMD to hide it. The pin forces 18 back-to-back
// ds_read_b128 + one lgkmcnt wait; the 88 FMAs then run from registers.
// VGPR ~110 is free: occupancy is LDS-bound (67KB -> 2 blocks/CU), cap 128.
__global__ __launch_bounds__(NTHREADS, 4)
void ssim_tile_kernel(const float* __restrict__ img1, const float* __restrict__ img2,
                      float* __restrict__ bsums, W11 wt) {
    __shared__ f32x4 sE[TH][LWE];   // 67,072 B
    __shared__ float redw[NTHREADS / 64];

    // XCD-aware bijective remap (NBLK % 8 == 0): each XCD sweeps 6 whole
    // planes in ascending band order -> band halos hit its own L2.
    const int bid   = blockIdx.x;
    const int sbid  = (bid & 7) * (NBLK / 8) + (bid >> 3);
    const int plane = sbid >> 6;              // sbid / NBANDS
    const int band  = sbid & (NBANDS - 1);

    const int r0 = band * TH - KR;
    const float* __restrict__ p1 = img1 + (size_t)plane * (IMG_H * IMG_W);
    const float* __restrict__ p2 = img2 + (size_t)plane * (IMG_H * IMG_W);
    const int tid = threadIdx.x;

    // Zero-fill the 12 alignment-halo elems (cols -6..-1, 512..517) x 8 rows.
    if (tid < 128) {
        const int h = tid & 15;
        if (h < 12) {
            const int r = tid >> 4;                    // 0..7
            const int e = (h < 6) ? h : (512 + h);
            sE[r][swz(e)] = (f32x4){0.f, 0.f, 0.f, 0.f};
        }
    }

    // ---- Phase A: vertical 11-tap conv, one column per thread ----
    float av[NR], bv[NR];
    {
        const float* __restrict__ g1 = p1 + tid;
        const float* __restrict__ g2 = p2 + tid;
        if (r0 >= 0 && r0 + NR <= IMG_H) {
            #pragma unroll
            for (int j = 0; j < NR; ++j) {
                av[j] = g1[(r0 + j) * IMG_W];
                bv[j] = g2[(r0 + j) * IMG_W];
            }
        } else {
            #pragma unroll
            for (int j = 0; j < NR; ++j) {
                const int  rr  = r0 + j;
                const bool ok  = (rr >= 0) && (rr < IMG_H);   // block-uniform
                const int  rrc = min(max(rr, 0), IMG_H - 1);
                const float a = g1[rrc * IMG_W];
                const float b = g2[rrc * IMG_W];
                av[j] = ok ? a : 0.f;
                bv[j] = ok ? b : 0.f;
            }
        }
    }

    f32x4 acc[TH];
    #pragma unroll
    for (int r = 0; r < TH; ++r) acc[r] = (f32x4){0.f, 0.f, 0.f, 0.f};

    #pragma unroll
    for (int j = 0; j < NR; ++j) {
        const float a = av[j], b = bv[j];
        f32x4 pv; pv.x = a; pv.y = b;
        pv.z = fmaf(a, a, b * b); pv.w = a * b;
        #pragma unroll
        for (int r = 0; r < TH; ++r) {
            const int k = j - r;                      // compile-time
            if (k >= 0 && k < KS) {
                f32x4 wv; wv.x = wt.w[k]; wv.y = wt.w[k];
                wv.z = wt.w[k]; wv.w = wt.w[k];
                acc[r] = __builtin_elementwise_fma(wv, pv, acc[r]);
            }
        }
    }
    {
        const int slot = swz(tid + 6);
        #pragma unroll
        for (int r = 0; r < TH; ++r) sE[r][slot] = acc[r];
    }
    __syncthreads();

    // ---- Phase B: horizontal conv + SSIM map; 1 row x 8 consecutive cols ----
    const float C1f = 0.0001f;   // 0.01^2
    const float C2f = 0.0009f;   // 0.03^2
    const int g  = tid >> 6;             // 8 rows x 64 lanes
    const int L  = tid & 63;
    const int eb = (L << 3) + 1;         // cols 8L..8L+7 need elems eb..eb+17

    f32x4 x[18];
    #pragma unroll
    for (int i = 0; i < 18; ++i) x[i] = sE[g][swz(eb + i)];
    // Force the WHOLE 18-elem window co-live: 18 back-to-back ds_read_b128,
    // one lgkmcnt wait, then the 88 FMAs run purely from registers.
    asm volatile("" ::
        "v"(x[0]),  "v"(x[1]),  "v"(x[2]),  "v"(x[3]),  "v"(x[4]),  "v"(x[5]),
        "v"(x[6]),  "v"(x[7]),  "v"(x[8]),  "v"(x[9]),  "v"(x[10]), "v"(x[11]),
        "v"(x[12]), "v"(x[13]), "v"(x[14]), "v"(x[15]), "v"(x[16]), "v"(x[17]));

    float lsum = 0.f;
    #pragma unroll
    for (int jj = 0; jj < 8; ++jj) {
        f32x4 c;
        {
            f32x4 wv; wv.x = wt.w[0]; wv.y = wt.w[0];
            wv.z = wt.w[0]; wv.w = wt.w[0];
            c = wv * x[jj];
        }
        #pragma unroll
        for (int k = 1; k < KS; ++k) {
            f32x4 wv; wv.x = wt.w[k]; wv.y = wt.w[k];
            wv.z = wt.w[k]; wv.w = wt.w[k];
            c = __builtin_elementwise_fma(wv, x[jj + k], c);
        }
        const float m1 = c.x, m2 = c.y;
        const float pp = c.z, ab = c.w;
        const float mu11 = m1 * m1;
        const float mu22 = m2 * m2;
        const float mu12 = m1 * m2;
        const float t     = mu11 + mu22;
        const float sigpp = pp - t;              // sigma1_sq + sigma2_sq
        const float sig12 = ab - mu12;
        const float num = fmaf(2.f, mu12, C1f) * fmaf(2.f, sig12, C2f);
        const float den = (t + C1f) * (sigpp + C2f);
        lsum = fmaf(num, __builtin_amdgcn_rcpf(den), lsum);
    }

    // ---- reduce: wave shuffle, then per-wave partials ----
    #pragma unroll
    for (int off = 32; off > 0; off >>= 1) lsum += __shfl_down(lsum, off);
    if ((tid & 63) == 0) redw[tid >> 6] = lsum;
    __syncthreads();
    if (tid == 0) {
        float t = 0.f;
        #pragma unroll
        for (int w = 0; w < NTHREADS / 64; ++w) t += redw[w];
        bsums[sbid] = t;
    }
}

// Final reduce in double (fp32 sequential sum of the 1.26e7-magnitude total
// would exceed the 2.6e-4 threshold).
__global__ __launch_bounds__(256)
void ssim_reduce_kernel(const float4* __restrict__ bsums, int n4,
                        float* __restrict__ out, double inv_count) {
    __shared__ double red[256];
    double acc = 0.0;
    for (int i = threadIdx.x; i < n4; i += 256) {
        const float4 v = bsums[i];
        acc += (double)v.x + (double)v.y + (double)v.z + (double)v.w;
    }
    red[threadIdx.x] = acc;
    __syncthreads();
    #pragma unroll
    for (int off = 128; off > 0; off >>= 1) {
        if (threadIdx.x < off) red[threadIdx.x] += red[threadIdx.x + off];
        __syncthreads();
    }
    if (threadIdx.x == 0) out[0] = (float)(red[0] * inv_count);
}

extern "C" void kernel_launch(void* const* d_in, const int* in_sizes, int n_in,
                              void* d_out, int out_size, void* d_ws, size_t ws_size,
                              hipStream_t stream) {
    const float* img1 = (const float*)d_in[0];
    const float* img2 = (const float*)d_in[1];
    float* out = (float*)d_out;
    float* bsums = (float*)d_ws;

    // Gaussian weights, computed in double like the numpy reference.
    W11 wt;
    {
        double g[KS], sum = 0.0;
        for (int i = 0; i < KS; ++i) {
            const double x = (double)(i - KR);
            g[i] = exp(-(x * x) / (2.0 * 1.5 * 1.5));
            sum += g[i];
        }
        for (int i = 0; i < KS; ++i) wt.w[i] = (float)(g[i] / sum);
    }

    ssim_tile_kernel<<<dim3(NBLK), NTHREADS, 0, stream>>>(img1, img2, bsums, wt);

    const double inv_count = 1.0 / ((double)NPLANES * IMG_H * IMG_W);
    ssim_reduce_kernel<<<1, 256, 0, stream>>>((const float4*)bsums, NBLK / 4,
                                              out, inv_count);
}